// Round 4
// baseline (92.084 us; speedup 1.0000x reference)
//
#include <hip/hip_runtime.h>
#include <math.h>

// Poincare contrastive loss, N=4096, D=8, TEMP=0.5.
// sim[i][j] = 1/(1+arcosh(x_ij)), x_ij = 1 + 2*sqdist/((1-sqc_i)(1-sqc_j))
// Rewrite: u = P_i . Q_j  (10-term dot, u = x-1 >= 0 exactly)
//   Q_j = [z_j(8), inv_j, inv_j*raw_j],  inv = 1/(1-min(raw,BOUNDARY))
//   P_i = [-4*inv_i*z_i(8), 2*inv_i*raw_i, 2*inv_i]
// loss = mean_i -(2*sim[i,partner] - log(sum_{j!=i} exp(2*sim[i][j])))
//
// ROUND-16: PWL LUT replaces the trans chain (-6us; r0 was trans-bound,
//   VALUBusy*wall matches 16 quarter-rate trans/cp exactly).
// ROUND-17/18: DPP hoist (neutral), Q off LDS pipe (-3.5us). Accounting:
//   dur = 39.5 fill + pair + ~14 fixed; pair now ~34us vs ~10us issue floor
//   -> per-block overhead + unhidden latency dominate, not throughput.
// ROUND-19 (this round): amortize 2x. R=4 rows/thread (i-tile 1024,
//   NTILE 1152): halves per-element DPP epilogue, LUT staging, P build,
//   tile decode, atomics, tail, and redundant Q loads. Q-groups of 2 (20
//   regs - qg[4] was 40 regs, a miscount that plus launch_bounds(.,4)
//   forced spills at VGPR_Count 48). No min-occupancy bound: let colacc
//   live in VGPRs (~120). reduce: 32x256 DPP instead of 8x1024 tree.
// Non-pair fixed: 39.5us harness 256MiB poison-fill - untouchable.

#define D 8
#define QS 12                // padded Q stride (floats) -> 48B, 16B-aligned
#define TWO_N 8192
#define HALF_N 4096
constexpr int BLOCK = 256;
constexpr int JC    = 32;    // j-chunk per block
constexpr int ITILE = 1024;  // i-rows per block (4 rows/thread)
constexpr int NTILE = 1152;  // sum_{b=0}^{7} (256 - 32b)
constexpr int NSEG  = 368;   // 23 octaves x 16 segments, u in [2^-16, 2^7)
constexpr int SEG_LO = 1776; // (111 << 4): bits>>19 of u = 2^-16
#define BOUNDARY (1.0f - 1e-5f)
#define LN2 0.6931471805599453f

typedef float f32x2 __attribute__((ext_vector_type(2)));

__device__ __forceinline__ float frcp(float x)  { return __builtin_amdgcn_rcpf(x); }
__device__ __forceinline__ float fsqrt(float x) { return __builtin_amdgcn_sqrtf(x); }
__device__ __forceinline__ float flog2(float x) { return __builtin_amdgcn_logf(x); }
__device__ __forceinline__ f32x2 splat(float v) { return (f32x2){v, v}; }

// DPP wave64 sum: result in lane 63.
__device__ __forceinline__ float dpp_wave_sum(float v) {
    int x;
    x = __builtin_amdgcn_update_dpp(0, __float_as_int(v), 0x111, 0xf, 0xf, false); // row_shr:1
    v += __int_as_float(x);
    x = __builtin_amdgcn_update_dpp(0, __float_as_int(v), 0x112, 0xf, 0xf, false); // row_shr:2
    v += __int_as_float(x);
    x = __builtin_amdgcn_update_dpp(0, __float_as_int(v), 0x114, 0xf, 0xe, false); // row_shr:4
    v += __int_as_float(x);
    x = __builtin_amdgcn_update_dpp(0, __float_as_int(v), 0x118, 0xf, 0xc, false); // row_shr:8
    v += __int_as_float(x);
    x = __builtin_amdgcn_update_dpp(0, __float_as_int(v), 0x142, 0xa, 0xf, false); // row_bcast:15
    v += __int_as_float(x);
    x = __builtin_amdgcn_update_dpp(0, __float_as_int(v), 0x143, 0xc, 0xf, false); // row_bcast:31
    v += __int_as_float(x);
    return v;   // lane 63 = full sum
}

// ---- prep: Q[row] = [z(8), inv, inv*raw, 0, 0]; zero denom + out; LUT ----
__global__ __launch_bounds__(256) void prep_kernel(
    const float* __restrict__ zi, const float* __restrict__ zj,
    float* __restrict__ q, float* __restrict__ denom, float* __restrict__ out,
    float2* __restrict__ tab)
{
    const int row = blockIdx.x * 256 + threadIdx.x;
    const float* src = (row < HALF_N) ? (zi + (size_t)row * D)
                                      : (zj + (size_t)(row - HALF_N) * D);
    float4 a = *(const float4*)(src);
    float4 b = *(const float4*)(src + 4);
    float raw = a.x*a.x + a.y*a.y + a.z*a.z + a.w*a.w
              + b.x*b.x + b.y*b.y + b.z*b.z + b.w*b.w;
    float inv = frcp(1.0f - fminf(raw, BOUNDARY));
    float* dst = q + (size_t)row * QS;
    *(float4*)(dst)     = a;
    *(float4*)(dst + 4) = b;
    *(float4*)(dst + 8) = make_float4(inv, inv * raw, 0.0f, 0.0f);
    denom[row] = 0.0f;
    if (row == 0) out[0] = 0.0f;

    // build PWL LUT for g(u) = exp(2/(1+arcosh(1+u))), log2-spaced segments.
    if (row < NSEG) {
        const int m0 = row + SEG_LO;
        const int m1 = m0 + 1;
        float ua_f = __uint_as_float(((unsigned)(m0 >> 4) << 23) | ((unsigned)(m0 & 15) << 19));
        float ub_f = __uint_as_float(((unsigned)(m1 >> 4) << 23) | ((unsigned)(m1 & 15) << 19));
        double ua = (double)ua_f, ub = (double)ub_f;
        double ga = exp(2.0 / (1.0 + log(1.0 + ua + sqrt(ua * (ua + 2.0)))));
        double gb = exp(2.0 / (1.0 + log(1.0 + ub + sqrt(ub * (ub + 2.0)))));
        double sl = (gb - ga) / (ub - ua);
        double ic = ga - sl * ua;
        tab[row] = make_float2((float)sl, (float)ic);
    }
}

struct QCol { float4 a; float4 b; float2 c; };

// one column's 10-term dot; accumulator starts at 0 so result is u = x-1
__device__ __forceinline__ f32x2 dot_col(const f32x2* __restrict__ p2,
                                         const QCol& qc)
{
    f32x2 x = splat(0.0f);
    x = __builtin_elementwise_fma(p2[0], splat(qc.a.x), x);
    x = __builtin_elementwise_fma(p2[1], splat(qc.a.y), x);
    x = __builtin_elementwise_fma(p2[2], splat(qc.a.z), x);
    x = __builtin_elementwise_fma(p2[3], splat(qc.a.w), x);
    x = __builtin_elementwise_fma(p2[4], splat(qc.b.x), x);
    x = __builtin_elementwise_fma(p2[5], splat(qc.b.y), x);
    x = __builtin_elementwise_fma(p2[6], splat(qc.b.z), x);
    x = __builtin_elementwise_fma(p2[7], splat(qc.b.w), x);
    x = __builtin_elementwise_fma(p2[8], splat(qc.c.x), x);
    x = __builtin_elementwise_fma(p2[9], splat(qc.c.y), x);
    return x;
}

// e = exp(2*sim) via PWL table; u must be >= 0
__device__ __forceinline__ float lut1(float u, const float2* __restrict__ tab)
{
    int t = (int)(__float_as_uint(u) >> 19) - SEG_LO;
    t = (t < 0) ? 0 : t;
    t = (t > NSEG - 1) ? NSEG - 1 : t;
    float2 si = tab[t];
    return fmaf(si.x, u, si.y);
}

// build packed P for two rows
__device__ __forceinline__ void build_p2(const float* __restrict__ q,
                                         int r0, int r1, f32x2* p2)
{
    const float* q0 = q + (size_t)r0 * QS;
    const float* q1 = q + (size_t)r1 * QS;
    float4 a0 = *(const float4*)(q0), b0 = *(const float4*)(q0 + 4);
    float4 c0 = *(const float4*)(q0 + 8);
    float4 a1 = *(const float4*)(q1), b1 = *(const float4*)(q1 + 4);
    float4 c1 = *(const float4*)(q1 + 8);
    float m0 = -4.0f * c0.x, m1 = -4.0f * c1.x;
    p2[0] = (f32x2){m0 * a0.x, m1 * a1.x};
    p2[1] = (f32x2){m0 * a0.y, m1 * a1.y};
    p2[2] = (f32x2){m0 * a0.z, m1 * a1.z};
    p2[3] = (f32x2){m0 * a0.w, m1 * a1.w};
    p2[4] = (f32x2){m0 * b0.x, m1 * b1.x};
    p2[5] = (f32x2){m0 * b0.y, m1 * b1.y};
    p2[6] = (f32x2){m0 * b0.z, m1 * b1.z};
    p2[7] = (f32x2){m0 * b0.w, m1 * b1.w};
    p2[8] = (f32x2){2.0f * c0.y, 2.0f * c1.y};
    p2[9] = (f32x2){2.0f * c0.x, 2.0f * c1.x};
}

// ---- symmetric pair kernel: 4 rows/thread, reg col-accs, batch DPP end ----
__global__ __launch_bounds__(BLOCK) void pair_kernel(
    const float* __restrict__ q, const float2* __restrict__ gtab,
    float* __restrict__ denom)
{
    __shared__ alignas(16) float2 stab[NSEG];  // 2.9 KB PWL table
    __shared__ float swave[4][JC];             // per-wave column sums

    const int tid = threadIdx.x;

    // tile decode: t -> (b = i-block of 1024 rows, jbase)
    const int t = blockIdx.x;
    int b = 0;
    #pragma unroll
    for (int k = 1; k < 8; ++k)
        b += (t >= (256 * k - 16 * k * (k - 1))) ? 1 : 0;
    const int Fb    = 256 * b - 16 * b * (b - 1);
    const int ibase = ITILE * b;
    const int jbase = ibase + 32 * (t - Fb);
    const bool diag = (jbase < ibase + ITILE);

    // stage LUT (184 float4)
    if (tid < NSEG / 2)
        ((float4*)stab)[tid] = ((const float4*)gtab)[tid];

    // own four rows -> two packed P sets
    const int irow0 = ibase + tid;
    const int irow1 = irow0 + 256;
    const int irow2 = irow0 + 512;
    const int irow3 = irow0 + 768;
    f32x2 pA[10], pB[10];
    build_p2(q, irow0, irow1, pA);
    build_p2(q, irow2, irow3, pB);

    f32x2 accA = splat(0.0f), accB = splat(0.0f);
    float colacc[JC];
    #pragma unroll
    for (int c = 0; c < JC; ++c) colacc[c] = 0.0f;

    __syncthreads();   // stab ready

    // FULL unroll: colacc indices must be compile-time constants (VGPR array)
    #pragma unroll
    for (int jp = 0; jp < JC / 2; ++jp) {
        const int jj0 = 2 * jp, jj1 = 2 * jp + 1;
        const float* qc0 = q + (size_t)(jbase + jj0) * QS;

        QCol q0, q1;
        q0.a = *(const float4*)(qc0);
        q0.b = *(const float4*)(qc0 + 4);
        q0.c = *(const float2*)(qc0 + 8);
        q1.a = *(const float4*)(qc0 + QS);
        q1.b = *(const float4*)(qc0 + QS + 4);
        q1.c = *(const float2*)(qc0 + QS + 8);

        f32x2 uA0 = dot_col(pA, q0);
        f32x2 uB0 = dot_col(pB, q0);
        f32x2 uA1 = dot_col(pA, q1);
        f32x2 uB1 = dot_col(pB, q1);
        uA0 = __builtin_elementwise_max(uA0, splat(0.0f));
        uB0 = __builtin_elementwise_max(uB0, splat(0.0f));
        uA1 = __builtin_elementwise_max(uA1, splat(0.0f));
        uB1 = __builtin_elementwise_max(uB1, splat(0.0f));
        f32x2 eA0 = (f32x2){lut1(uA0.x, stab), lut1(uA0.y, stab)};
        f32x2 eB0 = (f32x2){lut1(uB0.x, stab), lut1(uB0.y, stab)};
        f32x2 eA1 = (f32x2){lut1(uA1.x, stab), lut1(uA1.y, stab)};
        f32x2 eB1 = (f32x2){lut1(uB1.x, stab), lut1(uB1.y, stab)};

        if (diag) {
            const int j0 = jbase + jj0, j1 = jbase + jj1;
            eA0.x = (j0 > irow0) ? eA0.x : 0.0f;
            eA0.y = (j0 > irow1) ? eA0.y : 0.0f;
            eB0.x = (j0 > irow2) ? eB0.x : 0.0f;
            eB0.y = (j0 > irow3) ? eB0.y : 0.0f;
            eA1.x = (j1 > irow0) ? eA1.x : 0.0f;
            eA1.y = (j1 > irow1) ? eA1.y : 0.0f;
            eB1.x = (j1 > irow2) ? eB1.x : 0.0f;
            eB1.y = (j1 > irow3) ? eB1.y : 0.0f;
        }
        accA += eA0; accA += eA1;
        accB += eB0; accB += eB1;
        colacc[jj0] += (eA0.x + eA0.y) + (eB0.x + eB0.y);
        colacc[jj1] += (eA1.x + eA1.y) + (eB1.x + eB1.y);
    }

    // batch column reduce: 32 independent DPP chains (full ILP), once.
    const int wid  = tid >> 6;
    const bool l63 = ((tid & 63) == 63);
    #pragma unroll
    for (int c = 0; c < JC; ++c) {
        float s = dpp_wave_sum(colacc[c]);
        if (l63) swave[wid][c] = s;
    }

    __syncthreads();
    if (tid < JC) {
        float tot = swave[0][tid] + swave[1][tid] + swave[2][tid] + swave[3][tid];
        atomicAdd(&denom[jbase + tid], tot);
    }
    atomicAdd(&denom[irow0], accA.x);
    atomicAdd(&denom[irow1], accA.y);
    atomicAdd(&denom[irow2], accB.x);
    atomicAdd(&denom[irow3], accB.y);
}

// ---- epilogue: 32 blocks x 256, one row/thread; denom excludes self ----
__global__ __launch_bounds__(256) void reduce_kernel(
    const float* __restrict__ zi, const float* __restrict__ zj,
    const float* __restrict__ denom, float* __restrict__ out)
{
    __shared__ float swred[4];
    const int tid = threadIdx.x;
    const int i   = blockIdx.x * 256 + tid;

    const int base = (i < HALF_N) ? i : (i - HALF_N);
    const float* pa = (i < HALF_N) ? (zi + (size_t)base * D) : (zj + (size_t)base * D);
    const float* pb = (i < HALF_N) ? (zj + (size_t)base * D) : (zi + (size_t)base * D);
    float4 a0 = *(const float4*)(pa), a1 = *(const float4*)(pa + 4);
    float4 b0 = *(const float4*)(pb), b1 = *(const float4*)(pb + 4);
    float rawa = a0.x*a0.x + a0.y*a0.y + a0.z*a0.z + a0.w*a0.w
               + a1.x*a1.x + a1.y*a1.y + a1.z*a1.z + a1.w*a1.w;
    float rawb = b0.x*b0.x + b0.y*b0.y + b0.z*b0.z + b0.w*b0.w
               + b1.x*b1.x + b1.y*b1.y + b1.z*b1.z + b1.w*b1.w;
    float dot  = a0.x*b0.x + a0.y*b0.y + a0.z*b0.z + a0.w*b0.w
               + a1.x*b1.x + a1.y*b1.y + a1.z*b1.z + a1.w*b1.w;
    float sqd  = fmaxf(rawa + rawb - 2.0f * dot, 0.0f);
    float inva = frcp(1.0f - fminf(rawa, BOUNDARY));
    float invb = frcp(1.0f - fminf(rawb, BOUNDARY));
    float x    = fmaf(2.0f * sqd, inva * invb, 1.0f);
    float t    = fmaf(x, x, -1.0f);
    float s    = fsqrt(fmaxf(t, 0.0f));
    float dist = flog2(x + s) * LN2;
    float sim  = frcp(1.0f + dist);               // positive pair similarity
    float dlog = flog2(denom[i]) * LN2;           // self already excluded
    float term = -(2.0f * sim - dlog);

    float ws = dpp_wave_sum(term);
    if ((tid & 63) == 63) swred[tid >> 6] = ws;
    __syncthreads();
    if (tid == 0)
        atomicAdd(out, (swred[0] + swred[1] + swred[2] + swred[3])
                           * (1.0f / (float)TWO_N));
}

extern "C" void kernel_launch(void* const* d_in, const int* in_sizes, int n_in,
                              void* d_out, int out_size, void* d_ws, size_t ws_size,
                              hipStream_t stream) {
    const float* zi = (const float*)d_in[0];
    const float* zj = (const float*)d_in[1];

    float*  denom = (float*)d_ws;                 // [8192]
    float*  q     = denom + TWO_N;                // [8192 * 12]
    float2* tab   = (float2*)(q + (size_t)TWO_N * QS);  // [368]

    prep_kernel<<<TWO_N / 256, 256, 0, stream>>>(zi, zj, q, denom, (float*)d_out, tab);

    pair_kernel<<<NTILE, BLOCK, 0, stream>>>(q, tab, denom);

    reduce_kernel<<<TWO_N / 256, 256, 0, stream>>>(zi, zj, denom, (float*)d_out);
}

// Round 5
// 90.687 us; speedup vs baseline: 1.0154x; 1.0154x over previous
//
#include <hip/hip_runtime.h>
#include <math.h>

// Poincare contrastive loss, N=4096, D=8, TEMP=0.5.
// sim[i][j] = 1/(1+arcosh(x_ij)), x_ij = 1 + 2*sqdist/((1-sqc_i)(1-sqc_j))
// u = x-1 decomposed as u = A - 4*inv_sel*S,  S = z_i.z_j,
//   A = 2*inv_i*inv_j*(raw_i+raw_j), inv_sel = inv of the SMALLER index side
// (bit-compatible with the long-standing triangle kernel's P.Q values).
// e = exp(2*sim) via 368-seg PWL LUT on u (log2-indexed), built in prep.
// loss = mean_i -(2*sim[i,partner] - log(sum_{j!=i} e_ij))
//
// ROUND-16..18: LUT (-6us), colacc hoist (neutral), scalar Q (-3.5us).
// ROUND-19: R=4 amortization REGRESSED (92.1) - residency/backfill loss.
// ROUND-20 (this round): full-matrix occupancy-first rewrite. r3's pair ran
// ~34us vs ~9.6us issue floor at only 4 waves/SIMD (VGPR ~110 from colacc+
// qg+p2). Full matrix does 2x dots but kills colacc, DPP epilogue, column
// atomics, diag masking, decode -> ~46 VGPR, launch_bounds(256,8):
// 2048 blocks = EXACTLY 8 blocks/CU all resident, 8 waves/SIMD, zero tail.
// Row sums -> coalesced part[jc][row] stores (4MB, ~0.7us) instead of 1.2M
// atomics; reduce sums 128 partials/row and subtracts the self term via the
// same LUT. Numerics identical to triangle modulo summation order (~1e-7).
// Non-pair fixed: 39.5us harness 256MiB poison-fill - untouchable.

#define D 8
#define QS 12                // padded Q stride (floats) -> 48B, 16B-aligned
#define TWO_N 8192
#define HALF_N 4096
constexpr int BLOCK   = 256;
constexpr int JC      = 64;    // j-columns per block
constexpr int IBLOCKS = 16;    // 8192 / 512
constexpr int JCHUNKS = 128;   // 8192 / JC
constexpr int NBLK    = IBLOCKS * JCHUNKS;  // 2048 = 8 blocks/CU exactly
constexpr int NSEG  = 368;   // 23 octaves x 16 segments, u in [2^-16, 2^7)
constexpr int SEG_LO = 1776; // (111 << 4): bits>>19 of u = 2^-16
#define BOUNDARY (1.0f - 1e-5f)
#define LN2 0.6931471805599453f

typedef float f32x2 __attribute__((ext_vector_type(2)));

__device__ __forceinline__ float frcp(float x)  { return __builtin_amdgcn_rcpf(x); }
__device__ __forceinline__ float fsqrt(float x) { return __builtin_amdgcn_sqrtf(x); }
__device__ __forceinline__ float flog2(float x) { return __builtin_amdgcn_logf(x); }
__device__ __forceinline__ f32x2 splat(float v) { return (f32x2){v, v}; }

// DPP wave64 sum: result in lane 63.
__device__ __forceinline__ float dpp_wave_sum(float v) {
    int x;
    x = __builtin_amdgcn_update_dpp(0, __float_as_int(v), 0x111, 0xf, 0xf, false); // row_shr:1
    v += __int_as_float(x);
    x = __builtin_amdgcn_update_dpp(0, __float_as_int(v), 0x112, 0xf, 0xf, false); // row_shr:2
    v += __int_as_float(x);
    x = __builtin_amdgcn_update_dpp(0, __float_as_int(v), 0x114, 0xf, 0xe, false); // row_shr:4
    v += __int_as_float(x);
    x = __builtin_amdgcn_update_dpp(0, __float_as_int(v), 0x118, 0xf, 0xc, false); // row_shr:8
    v += __int_as_float(x);
    x = __builtin_amdgcn_update_dpp(0, __float_as_int(v), 0x142, 0xa, 0xf, false); // row_bcast:15
    v += __int_as_float(x);
    x = __builtin_amdgcn_update_dpp(0, __float_as_int(v), 0x143, 0xc, 0xf, false); // row_bcast:31
    v += __int_as_float(x);
    return v;   // lane 63 = full sum
}

// ---- prep: Q[row] = [z(8), inv, inv*raw, 0, 0]; zero out; build LUT ----
__global__ __launch_bounds__(256) void prep_kernel(
    const float* __restrict__ zi, const float* __restrict__ zj,
    float* __restrict__ q, float* __restrict__ out, float2* __restrict__ tab)
{
    const int row = blockIdx.x * 256 + threadIdx.x;
    const float* src = (row < HALF_N) ? (zi + (size_t)row * D)
                                      : (zj + (size_t)(row - HALF_N) * D);
    float4 a = *(const float4*)(src);
    float4 b = *(const float4*)(src + 4);
    float raw = a.x*a.x + a.y*a.y + a.z*a.z + a.w*a.w
              + b.x*b.x + b.y*b.y + b.z*b.z + b.w*b.w;
    float inv = frcp(1.0f - fminf(raw, BOUNDARY));
    float* dst = q + (size_t)row * QS;
    *(float4*)(dst)     = a;
    *(float4*)(dst + 4) = b;
    *(float4*)(dst + 8) = make_float4(inv, inv * raw, 0.0f, 0.0f);
    if (row == 0) out[0] = 0.0f;

    // build PWL LUT for g(u) = exp(2/(1+arcosh(1+u))), log2-spaced segments.
    if (row < NSEG) {
        const int m0 = row + SEG_LO;
        const int m1 = m0 + 1;
        float ua_f = __uint_as_float(((unsigned)(m0 >> 4) << 23) | ((unsigned)(m0 & 15) << 19));
        float ub_f = __uint_as_float(((unsigned)(m1 >> 4) << 23) | ((unsigned)(m1 & 15) << 19));
        double ua = (double)ua_f, ub = (double)ub_f;
        double ga = exp(2.0 / (1.0 + log(1.0 + ua + sqrt(ua * (ua + 2.0)))));
        double gb = exp(2.0 / (1.0 + log(1.0 + ub + sqrt(ub * (ub + 2.0)))));
        double sl = (gb - ga) / (ub - ua);
        double ic = ga - sl * ua;
        tab[row] = make_float2((float)sl, (float)ic);
    }
}

// e = exp(2*sim) via PWL table; u must be >= 0
__device__ __forceinline__ float lut1(float u, const float2* __restrict__ tab)
{
    int t = (int)(__float_as_uint(u) >> 19) - SEG_LO;
    t = (t < 0) ? 0 : t;
    t = (t > NSEG - 1) ? NSEG - 1 : t;
    float2 si = tab[t];
    return fmaf(si.x, u, si.y);
}

// MODE: 0 = all j > i (inv_sel = inv_i, per-lane reg)
//       1 = all j < i (inv_sel = inv_j, per-col scalar)
//       2 = diagonal overlap (per-element select)
template<int MODE>
__device__ __forceinline__ f32x2 tile_loop(
    const float* __restrict__ q, const float2* __restrict__ stab, int jbase,
    const f32x2* __restrict__ s2, f32x2 t8, f32x2 t9, f32x2 m4,
    int irow0, int irow1)
{
    f32x2 acc = splat(0.0f);
    #pragma unroll 2
    for (int cc = 0; cc < JC; ++cc) {
        const float* qp = q + (size_t)(jbase + cc) * QS;   // wave-uniform
        float4 za = *(const float4*)(qp);
        float4 zb = *(const float4*)(qp + 4);
        float2 qc = *(const float2*)(qp + 8);              // {inv_j, inv_j*raw_j}

        f32x2 S = splat(0.0f);                             // z_i . z_j
        S = __builtin_elementwise_fma(s2[0], splat(za.x), S);
        S = __builtin_elementwise_fma(s2[1], splat(za.y), S);
        S = __builtin_elementwise_fma(s2[2], splat(za.z), S);
        S = __builtin_elementwise_fma(s2[3], splat(za.w), S);
        S = __builtin_elementwise_fma(s2[4], splat(zb.x), S);
        S = __builtin_elementwise_fma(s2[5], splat(zb.y), S);
        S = __builtin_elementwise_fma(s2[6], splat(zb.z), S);
        S = __builtin_elementwise_fma(s2[7], splat(zb.w), S);

        f32x2 A = t8 * splat(qc.x);                        // 2*inv_i*raw_i*inv_j
        A = __builtin_elementwise_fma(t9, splat(qc.y), A); // + 2*inv_i*inv_j*raw_j

        f32x2 msel;
        if (MODE == 0) {
            msel = m4;                                     // -4*inv_i
        } else {
            const float nm = -4.0f * qc.x;                 // -4*inv_j
            if (MODE == 1) {
                msel = splat(nm);
            } else {
                const int j = jbase + cc;
                msel.x = (j > irow0) ? m4.x : nm;
                msel.y = (j > irow1) ? m4.y : nm;
            }
        }
        f32x2 u = __builtin_elementwise_fma(S, msel, A);
        u = __builtin_elementwise_max(u, splat(0.0f));
        acc.x += lut1(u.x, stab);
        acc.y += lut1(u.y, stab);
    }
    return acc;
}

// ---- full-matrix pair kernel: 2048 blocks (8/CU), partial-store rowsums ----
__global__ __launch_bounds__(BLOCK, 8) void pair_kernel(
    const float* __restrict__ q, const float2* __restrict__ gtab,
    float* __restrict__ part)
{
    __shared__ alignas(16) float2 stab[NSEG];  // 2.9 KB PWL table

    const int tid   = threadIdx.x;
    const int ib    = blockIdx.x >> 7;               // i-block (16)
    const int jc    = blockIdx.x & (JCHUNKS - 1);    // j-chunk (128)
    const int ibase = ib * 512;
    const int jbase = jc * JC;

    if (tid < NSEG / 2)
        ((float4*)stab)[tid] = ((const float4*)gtab)[tid];

    // own two rows
    const int irow0 = ibase + tid;
    const int irow1 = irow0 + 256;
    f32x2 s2[8], t8, t9, m4;
    {
        const float* q0 = q + (size_t)irow0 * QS;
        const float* q1 = q + (size_t)irow1 * QS;
        float4 a0 = *(const float4*)(q0), b0 = *(const float4*)(q0 + 4);
        float2 c0 = *(const float2*)(q0 + 8);
        float4 a1 = *(const float4*)(q1), b1 = *(const float4*)(q1 + 4);
        float2 c1 = *(const float2*)(q1 + 8);
        s2[0] = (f32x2){a0.x, a1.x}; s2[1] = (f32x2){a0.y, a1.y};
        s2[2] = (f32x2){a0.z, a1.z}; s2[3] = (f32x2){a0.w, a1.w};
        s2[4] = (f32x2){b0.x, b1.x}; s2[5] = (f32x2){b0.y, b1.y};
        s2[6] = (f32x2){b0.z, b1.z}; s2[7] = (f32x2){b0.w, b1.w};
        t8 = (f32x2){2.0f * c0.y, 2.0f * c1.y};   // 2*inv*raw
        t9 = (f32x2){2.0f * c0.x, 2.0f * c1.x};   // 2*inv
        m4 = (f32x2){-4.0f * c0.x, -4.0f * c1.x}; // -4*inv
    }
    __syncthreads();   // stab ready

    f32x2 acc;
    if (jbase >= ibase + 512)
        acc = tile_loop<0>(q, stab, jbase, s2, t8, t9, m4, irow0, irow1);
    else if (jbase + JC <= ibase)
        acc = tile_loop<1>(q, stab, jbase, s2, t8, t9, m4, irow0, irow1);
    else
        acc = tile_loop<2>(q, stab, jbase, s2, t8, t9, m4, irow0, irow1);

    // coalesced partial row sums (includes j==i; reduce subtracts it)
    part[(size_t)jc * TWO_N + irow0] = acc.x;
    part[(size_t)jc * TWO_N + irow1] = acc.y;
}

// ---- epilogue: 32 blocks x 256; rowsum from partials, subtract self ----
__global__ __launch_bounds__(256) void reduce_kernel(
    const float* __restrict__ zi, const float* __restrict__ zj,
    const float* __restrict__ part, const float2* __restrict__ gtab,
    float* __restrict__ out)
{
    __shared__ float swred[4];
    const int tid = threadIdx.x;
    const int i   = blockIdx.x * 256 + tid;

    // sum the 128 j-chunk partials for this row (coalesced across lanes)
    float rs = 0.0f;
    {
        const float* pp = part + i;
        #pragma unroll 8
        for (int c = 0; c < JCHUNKS; ++c) rs += pp[(size_t)c * TWO_N];
    }

    const int base = (i < HALF_N) ? i : (i - HALF_N);
    const float* pa = (i < HALF_N) ? (zi + (size_t)base * D) : (zj + (size_t)base * D);
    const float* pb = (i < HALF_N) ? (zj + (size_t)base * D) : (zi + (size_t)base * D);
    float4 a0 = *(const float4*)(pa), a1 = *(const float4*)(pa + 4);
    float4 b0 = *(const float4*)(pb), b1 = *(const float4*)(pb + 4);
    float rawa = a0.x*a0.x + a0.y*a0.y + a0.z*a0.z + a0.w*a0.w
               + a1.x*a1.x + a1.y*a1.y + a1.z*a1.z + a1.w*a1.w;
    float rawb = b0.x*b0.x + b0.y*b0.y + b0.z*b0.z + b0.w*b0.w
               + b1.x*b1.x + b1.y*b1.y + b1.z*b1.z + b1.w*b1.w;
    float dot  = a0.x*b0.x + a0.y*b0.y + a0.z*b0.z + a0.w*b0.w
               + a1.x*b1.x + a1.y*b1.y + a1.z*b1.z + a1.w*b1.w;
    float sqd  = fmaxf(rawa + rawb - 2.0f * dot, 0.0f);
    float inva = frcp(1.0f - fminf(rawa, BOUNDARY));
    float invb = frcp(1.0f - fminf(rawb, BOUNDARY));
    float x    = fmaf(2.0f * sqd, inva * invb, 1.0f);
    float t    = fmaf(x, x, -1.0f);
    float s    = fsqrt(fmaxf(t, 0.0f));
    float dist = flog2(x + s) * LN2;
    float sim  = frcp(1.0f + dist);               // positive pair similarity

    // self term, mirroring pair's u = fma(S, -4*inv, A) with S=raw, A=4*inv^2*raw
    float cy = inva * rawa;
    float A  = (2.0f * cy) * inva;
    A = fmaf(2.0f * inva, cy, A);
    float us = fmaxf(fmaf(rawa, -4.0f * inva, A), 0.0f);
    float es = lut1(us, gtab);                    // same PWL -> exact cancel

    float denomv = rs - es;
    float dlog = flog2(denomv) * LN2;
    float term = -(2.0f * sim - dlog);

    float ws = dpp_wave_sum(term);
    if ((tid & 63) == 63) swred[tid >> 6] = ws;
    __syncthreads();
    if (tid == 0)
        atomicAdd(out, (swred[0] + swred[1] + swred[2] + swred[3])
                           * (1.0f / (float)TWO_N));
}

extern "C" void kernel_launch(void* const* d_in, const int* in_sizes, int n_in,
                              void* d_out, int out_size, void* d_ws, size_t ws_size,
                              hipStream_t stream) {
    const float* zi = (const float*)d_in[0];
    const float* zj = (const float*)d_in[1];

    float*  q    = (float*)d_ws;                        // [8192 * 12]
    float2* tab  = (float2*)(q + (size_t)TWO_N * QS);   // [368]
    float*  part = (float*)(tab + NSEG);                // [128 * 8192] = 4 MB

    prep_kernel<<<TWO_N / 256, 256, 0, stream>>>(zi, zj, q, (float*)d_out, tab);

    pair_kernel<<<NBLK, BLOCK, 0, stream>>>(q, tab, part);

    reduce_kernel<<<TWO_N / 256, 256, 0, stream>>>(zi, zj, part, tab, (float*)d_out);
}